// Round 7
// baseline (612.991 us; speedup 1.0000x reference)
//
#include <hip/hip_runtime.h>
#include <hip/hip_bf16.h>

typedef __bf16 bf16x8 __attribute__((ext_vector_type(8)));
typedef float  f32x4  __attribute__((ext_vector_type(4)));
typedef unsigned short ushort_t;

#define NN 468

// wext element offsets (ushort), fragment-major planes
#define W1H 0
#define W1L 8192
#define W2H 16384
#define W2L 49152
#define W3H 81920
#define W3L 114688

// LDS byte offsets (union pool, peak 79,360 B -> 2 blocks/CU)
#define L_Y1H 0        // 14336 B : Y1 hi, 7 tiles x 16 x 64
#define L_Y1L 14336    // 14336 B
#define L_X1S 28672    // 26112 B : X1 fp32 [102][64]
#define L_Y2H 54784    // 12288 B : Y2 hi, 6 tiles x 16 x 64 (k-chunk)
#define L_Y2L 67072    // 12288 B   (ends 79360)
#define L_XS  0        // 41984 B : X2 chunk fp32 [82][128]
#define L_Y3H 41984    // 16384 B : Y3 chunk hi, 4 tiles x 16 x 128
#define L_Y3L 58368    // 16384 B   (ends 74752)
#define L_POOL 74752   // 512 B

// ---------------------------------------------------------------------------
__device__ __forceinline__ void split_bf16(float w, ushort_t* hp, ushort_t* lp) {
    __hip_bfloat16 hb = __float2bfloat16(w);
    float hf = __bfloat162float(hb);
    __hip_bfloat16 lb = __float2bfloat16(w - hf);
    *hp = *(ushort_t*)&hb;
    *lp = *(ushort_t*)&lb;
}

__device__ __forceinline__ float dinv_of(int ri) {
    if (ri < 0 || ri >= NN) return 0.f;
    int lo = ri - 9; if (lo < 0) lo = 0;
    int hi = ri + 9; if (hi > NN - 1) hi = NN - 1;
    return 1.0f / sqrtf((float)(hi - lo + 1));
}

// fragment element offset within a [tiles][16rows][K] plane
__device__ __forceinline__ int frag_off(int r, int k, int K16) {
    // K16 = 16*K elements per tile
    return (r >> 4) * K16 + (k >> 5) * 512 + ((k >> 3) & 3) * 128
         + (r & 15) * 8 + (k & 7);
}

// ---------------------------------------------------------------------------
// fused: whole 3-layer GCN chain for one (64-row tile, batch) in LDS.
// Local row frames: Y1/X1 rows lr1: gr = r0-18+lr1 (0..111, X1 kept 0..101)
//                   Y2/X2 rows lr2: gr = r0-9+lr2  (0..95, valid < 82)
//                   Y3/X3 rows lr3: gr = r0+lr3    (0..63)
// ---------------------------------------------------------------------------
__global__ __launch_bounds__(256, 2) void fused(
    const float* __restrict__ Lm, const ushort_t* __restrict__ wext,
    const float* __restrict__ We, const float* __restrict__ be,
    const float* __restrict__ b1, const float* __restrict__ b2,
    const float* __restrict__ b3, float* __restrict__ partial)
{
    __shared__ __align__(16) char lds[79360];
    ushort_t* Y1h = (ushort_t*)(lds + L_Y1H);
    ushort_t* Y1l = (ushort_t*)(lds + L_Y1L);
    float*    X1s = (float*)(lds + L_X1S);
    ushort_t* Y2h = (ushort_t*)(lds + L_Y2H);
    ushort_t* Y2l = (ushort_t*)(lds + L_Y2L);
    float*    Xs  = (float*)(lds + L_XS);
    ushort_t* Y3h = (ushort_t*)(lds + L_Y3H);
    ushort_t* Y3l = (ushort_t*)(lds + L_Y3L);
    float*    pool = (float*)(lds + L_POOL);

    const int tid  = threadIdx.x;
    const int lane = tid & 63;
    const int wave = tid >> 6;
    const int wm = wave & 1, wn = wave >> 1;
    const int l15 = lane & 15, lg = lane >> 4;
    const int rt = blockIdx.x, b = blockIdx.y;
    const int r0 = rt * 64;

    // ================= stage 1: band1 (encoder fused) -> Y1 ================
    {
        const int c = tid & 63, s = tid >> 6;        // 4 slices x 28 rows
        const float w0 = We[c], w1 = We[64 + c], w2 = We[128 + c], bk = be[c];
        const float* Xb = Lm + (size_t)b * (NN * 3);
        float z[46];
        #pragma unroll
        for (int j = 0; j < 46; ++j) {
            int gr = r0 + s * 28 - 27 + j;
            float v = 0.f;
            if (gr >= 0 && gr < NN) {
                float x = bk + Xb[gr*3]*w0 + Xb[gr*3+1]*w1 + Xb[gr*3+2]*w2;
                v = x * dinv_of(gr);
            }
            z[j] = v;
        }
        float ws = 0.f;
        #pragma unroll
        for (int j = 0; j < 19; ++j) ws += z[j];
        #pragma unroll
        for (int rr = 0; rr < 28; ++rr) {
            if (rr) ws += z[rr + 18] - z[rr - 1];
            int lr1 = s * 28 + rr;
            float y = ws * dinv_of(r0 - 18 + lr1);
            int off = frag_off(lr1, c, 1024);
            split_bf16(y, Y1h + off, Y1l + off);
        }
    }
    __syncthreads();

    // ============ stage 2: kc loop — GEMM1 half-N, band2, GEMM2 partial ====
    f32x4 acc2[3][8] = {};
    #pragma unroll
    for (int kc = 0; kc < 2; ++kc) {
        // ---- GEMM1: Y1 @ W1[:, kc*64 .. +64) ----
        f32x4 acc1[4][2] = {};
        #pragma unroll
        for (int kt = 0; kt < 2; ++kt) {
            bf16x8 a[4][2];
            #pragma unroll
            for (int mt = 0; mt < 4; ++mt) {
                int t = wm * 4 + mt; if (t > 6) t = 6;
                int off = t * 1024 + kt * 512 + lane * 8;
                a[mt][0] = *(const bf16x8*)(Y1h + off);
                a[mt][1] = *(const bf16x8*)(Y1l + off);
            }
            #pragma unroll
            for (int nt = 0; nt < 2; ++nt) {
                int ntile = kc * 4 + wn * 2 + nt;
                int woff = ntile * 1024 + kt * 512 + lane * 8;
                bf16x8 wh = *(const bf16x8*)(wext + W1H + woff);
                bf16x8 wl = *(const bf16x8*)(wext + W1L + woff);
                #pragma unroll
                for (int mt = 0; mt < 4; ++mt) {
                    acc1[mt][nt] = __builtin_amdgcn_mfma_f32_16x16x32_bf16(
                        a[mt][0], wh, acc1[mt][nt], 0, 0, 0);
                    acc1[mt][nt] = __builtin_amdgcn_mfma_f32_16x16x32_bf16(
                        a[mt][0], wl, acc1[mt][nt], 0, 0, 0);
                    acc1[mt][nt] = __builtin_amdgcn_mfma_f32_16x16x32_bf16(
                        a[mt][1], wh, acc1[mt][nt], 0, 0, 0);
                }
            }
        }
        // ---- epilogue: X1s[lr1][cl] = relu(acc1 + b1) ----
        #pragma unroll
        for (int mt = 0; mt < 4; ++mt) {
            int t = wm * 4 + mt; if (t > 6) t = 6;
            #pragma unroll
            for (int nt = 0; nt < 2; ++nt) {
                int cl = wn * 32 + nt * 16 + l15;
                float bv = b1[kc * 64 + cl];
                #pragma unroll
                for (int r = 0; r < 4; ++r) {
                    int lr1 = t * 16 + lg * 4 + r;
                    if (lr1 < 102)
                        X1s[lr1 * 64 + cl] = fmaxf(acc1[mt][nt][r] + bv, 0.f);
                }
            }
        }
        __syncthreads();

        // ---- band2: X1s -> Y2 (k-chunk kc) ----
        {
            const int c = tid & 63, h = tid >> 6;    // 4 groups x 24 rows
            const int L0 = h * 24;
            float ws = 0.f;
            #pragma unroll
            for (int j = 0; j < 19; ++j)
                ws += dinv_of(r0 - 18 + L0 + j) * X1s[(L0 + j) * 64 + c];
            #pragma unroll
            for (int rr = 0; rr < 24; ++rr) {
                int lr2 = L0 + rr;
                if (rr) {
                    int ih = lr2 + 18; int ihc = ih > 101 ? 101 : ih;
                    ws += dinv_of(r0 - 18 + ih) * X1s[ihc * 64 + c]
                        - dinv_of(r0 - 18 + lr2 - 1) * X1s[(lr2 - 1) * 64 + c];
                }
                float y = (lr2 < 82) ? ws * dinv_of(r0 - 9 + lr2) : 0.f;
                int off = frag_off(lr2, c, 1024);
                split_bf16(y, Y2h + off, Y2l + off);
            }
        }
        __syncthreads();

        // ---- GEMM2 partial: Y2(k-chunk) @ W2[kc*64.., :] -> acc2 ----
        #pragma unroll
        for (int kt = 0; kt < 2; ++kt) {
            bf16x8 a[3][2];
            #pragma unroll
            for (int mt = 0; mt < 3; ++mt) {
                int off = (wm * 3 + mt) * 1024 + kt * 512 + lane * 8;
                a[mt][0] = *(const bf16x8*)(Y2h + off);
                a[mt][1] = *(const bf16x8*)(Y2l + off);
            }
            #pragma unroll
            for (int nt = 0; nt < 8; ++nt) {
                int ntile = nt * 2 + wn;             // interleaved n-tiles
                int woff = ntile * 2048 + (kc * 2 + kt) * 512 + lane * 8;
                bf16x8 wh = *(const bf16x8*)(wext + W2H + woff);
                bf16x8 wl = *(const bf16x8*)(wext + W2L + woff);
                #pragma unroll
                for (int mt = 0; mt < 3; ++mt) {
                    acc2[mt][nt] = __builtin_amdgcn_mfma_f32_16x16x32_bf16(
                        a[mt][0], wh, acc2[mt][nt], 0, 0, 0);
                    acc2[mt][nt] = __builtin_amdgcn_mfma_f32_16x16x32_bf16(
                        a[mt][0], wl, acc2[mt][nt], 0, 0, 0);
                    acc2[mt][nt] = __builtin_amdgcn_mfma_f32_16x16x32_bf16(
                        a[mt][1], wh, acc2[mt][nt], 0, 0, 0);
                }
            }
        }
        __syncthreads();
    }

    // ============ stage 3: nc loop — epi2, band3, GEMM3 partial ============
    f32x4 acc3[2][4] = {};
    #pragma unroll
    for (int nc = 0; nc < 2; ++nc) {
        // ---- epilogue2: acc2 chunk -> Xs fp32 [82][128] ----
        #pragma unroll
        for (int mt = 0; mt < 3; ++mt)
        #pragma unroll
        for (int q = 0; q < 4; ++q) {
            int nt = nc * 4 + q;
            int ngl = (nt * 2 + wn) * 16 + l15;      // global col 0..255
            int cl = ngl - nc * 128;                 // col in chunk
            float bv = b2[ngl];
            #pragma unroll
            for (int r = 0; r < 4; ++r) {
                int lr2 = (wm * 3 + mt) * 16 + lg * 4 + r;
                if (lr2 < 82)
                    Xs[lr2 * 128 + cl] = fmaxf(acc2[mt][nt][r] + bv, 0.f);
            }
        }
        __syncthreads();

        // ---- band3: Xs -> Y3 chunk ----
        {
            const int c = tid & 127, h = tid >> 7;   // 2 groups x 32 rows
            const int L0 = h * 32;
            float ws = 0.f;
            #pragma unroll
            for (int j = 0; j < 19; ++j)
                ws += dinv_of(r0 - 9 + L0 + j) * Xs[(L0 + j) * 128 + c];
            #pragma unroll
            for (int rr = 0; rr < 32; ++rr) {
                int lr3 = L0 + rr;
                if (rr) ws += dinv_of(r0 + lr3 + 9) * Xs[(lr3 + 18) * 128 + c]
                            - dinv_of(r0 + lr3 - 10) * Xs[(lr3 - 1) * 128 + c];
                float y = ws * dinv_of(r0 + lr3);
                int off = frag_off(lr3, c, 2048);
                split_bf16(y, Y3h + off, Y3l + off);
            }
        }
        __syncthreads();

        // ---- GEMM3 partial: Y3 chunk @ W3[nc*128.., :] -> acc3 ----
        #pragma unroll
        for (int kt = 0; kt < 4; ++kt) {
            bf16x8 a[2][2];
            #pragma unroll
            for (int mt = 0; mt < 2; ++mt) {
                int off = (wm * 2 + mt) * 2048 + kt * 512 + lane * 8;
                a[mt][0] = *(const bf16x8*)(Y3h + off);
                a[mt][1] = *(const bf16x8*)(Y3l + off);
            }
            #pragma unroll
            for (int nt = 0; nt < 4; ++nt) {
                int ntile = wn * 4 + nt;
                int woff = ntile * 4096 + (nc * 4 + kt) * 512 + lane * 8;
                bf16x8 wh = *(const bf16x8*)(wext + W3H + woff);
                bf16x8 wl = *(const bf16x8*)(wext + W3L + woff);
                #pragma unroll
                for (int mt = 0; mt < 2; ++mt) {
                    acc3[mt][nt] = __builtin_amdgcn_mfma_f32_16x16x32_bf16(
                        a[mt][0], wh, acc3[mt][nt], 0, 0, 0);
                    acc3[mt][nt] = __builtin_amdgcn_mfma_f32_16x16x32_bf16(
                        a[mt][0], wl, acc3[mt][nt], 0, 0, 0);
                    acc3[mt][nt] = __builtin_amdgcn_mfma_f32_16x16x32_bf16(
                        a[mt][1], wh, acc3[mt][nt], 0, 0, 0);
                }
            }
        }
        __syncthreads();
    }

    // ================= pool: column sums of relu(acc3 + b3) ================
    if (tid < 128) pool[tid] = 0.f;
    __syncthreads();
    #pragma unroll
    for (int nt = 0; nt < 4; ++nt) {
        float bv = b3[wn * 64 + nt * 16 + l15];
        float cs = 0.f;
        #pragma unroll
        for (int mt = 0; mt < 2; ++mt)
        #pragma unroll
        for (int r = 0; r < 4; ++r) {
            int rib = r0 + (wm * 2 + mt) * 16 + lg * 4 + r;
            if (rib < NN) cs += fmaxf(acc3[mt][nt][r] + bv, 0.f);
        }
        cs += __shfl_xor(cs, 16);
        cs += __shfl_xor(cs, 32);
        if (lane < 16) atomicAdd(&pool[wn * 64 + nt * 16 + lane], cs);
    }
    __syncthreads();
    if (tid < 128) partial[((size_t)b * 8 + rt) * 128 + tid] = pool[tid];
}

// ---------------------------------------------------------------------------
// wconv: W fp32 [K][N] -> bf16 hi/lo planes in fragment layout
// ---------------------------------------------------------------------------
__global__ __launch_bounds__(256) void wconv(
    const float* __restrict__ W1, const float* __restrict__ W2,
    const float* __restrict__ W3, ushort_t* __restrict__ wext)
{
    int i = blockIdx.x * 256 + threadIdx.x;
    float w; int off_h, off_l, idx;
    if (i < 8192) {                       // W1: K=64,  N=128
        int k = i >> 7, n = i & 127;
        w = W1[i]; idx = frag_off(n, k, 1024);  off_h = W1H; off_l = W1L;
    } else if (i < 40960) {               // W2: K=128, N=256
        int j = i - 8192;
        int k = j >> 8, n = j & 255;
        w = W2[j]; idx = frag_off(n, k, 2048);  off_h = W2H; off_l = W2L;
    } else if (i < 73728) {               // W3: K=256, N=128
        int j = i - 40960;
        int k = j >> 7, n = j & 127;
        w = W3[j]; idx = frag_off(n, k, 4096);  off_h = W3H; off_l = W3L;
    } else return;
    split_bf16(w, wext + off_h + idx, wext + off_l + idx);
}

// ---------------------------------------------------------------------------
// head: gf = mean-pool reduce; features = relu(gf@Wf+bf); out = feats@Wc+bc
// ---------------------------------------------------------------------------
__global__ __launch_bounds__(512) void head_kernel(
    const float* __restrict__ partial, const float* __restrict__ Wf,
    const float* __restrict__ bf, const float* __restrict__ Wc,
    const float* __restrict__ bc, float* __restrict__ dout)
{
    __shared__ float gfs[128];
    __shared__ float feats[512];
    int b = blockIdx.x, t = threadIdx.x;
    if (t < 128) {
        const float* p = partial + (size_t)b * 1024;
        float s = 0.f;
        #pragma unroll
        for (int tt = 0; tt < 8; ++tt) s += p[tt * 128 + t];
        s *= (1.0f / 468.0f);
        gfs[t] = s;
        dout[65792 + b * 128 + t] = s;       // graph_features
    }
    __syncthreads();
    float a = bf[t];
    for (int k = 0; k < 128; ++k) a += gfs[k] * Wf[k * 512 + t];
    a = fmaxf(a, 0.f);
    dout[256 + b * 512 + t] = a;             // features
    feats[t] = a;
    __syncthreads();
    if (t < 64) {
        float s0 = 0.f, s1 = 0.f;
        for (int c = t; c < 512; c += 64) {
            float f = feats[c];
            s0 += f * Wc[c * 2 + 0];
            s1 += f * Wc[c * 2 + 1];
        }
        #pragma unroll
        for (int off = 32; off; off >>= 1) {
            s0 += __shfl_down(s0, off);
            s1 += __shfl_down(s1, off);
        }
        if (t == 0) {
            dout[b * 2 + 0] = s0 + bc[0];
            dout[b * 2 + 1] = s1 + bc[1];
        }
    }
}

// ---------------------------------------------------------------------------
extern "C" void kernel_launch(void* const* d_in, const int* in_sizes, int n_in,
                              void* d_out, int out_size, void* d_ws, size_t ws_size,
                              hipStream_t stream)
{
    const float* landmarks = (const float*)d_in[0];
    const float* W_enc     = (const float*)d_in[1];
    const float* b_enc     = (const float*)d_in[2];
    const float* W1        = (const float*)d_in[3];
    const float* b1        = (const float*)d_in[4];
    const float* W2        = (const float*)d_in[5];
    const float* b2        = (const float*)d_in[6];
    const float* W3        = (const float*)d_in[7];
    const float* b3        = (const float*)d_in[8];
    const float* W_fus     = (const float*)d_in[9];
    const float* b_fus     = (const float*)d_in[10];
    const float* W_cls     = (const float*)d_in[11];
    const float* b_cls     = (const float*)d_in[12];
    float* out = (float*)d_out;

    char* ws = (char*)d_ws;
    ushort_t* wext = (ushort_t*)(ws + 0);        // 294,912 B
    float* partial = (float*)(ws + 294912);      // 524,288 B

    wconv<<<288, 256, 0, stream>>>(W1, W2, W3, wext);
    fused<<<dim3(8, 128), 256, 0, stream>>>(
        landmarks, wext, W_enc, b_enc, b1, b2, b3, partial);
    head_kernel<<<128, 512, 0, stream>>>(partial, W_fus, b_fus, W_cls, b_cls, out);
}

// Round 8
// 214.575 us; speedup vs baseline: 2.8568x; 2.8568x over previous
//
#include <hip/hip_runtime.h>
#include <hip/hip_bf16.h>

typedef __bf16 bf16x8 __attribute__((ext_vector_type(8)));
typedef float  f32x4  __attribute__((ext_vector_type(4)));
typedef unsigned short ushort_t;

#define NN 468

// wext element offsets (ushort), fragment-major planes
#define W1H 0
#define W1L 8192
#define W2H 16384
#define W2L 49152
#define W3H 81920
#define W3L 114688

// LDS byte offsets (80 KB exactly -> 2 blocks/CU)
#define L_X1   0        // [68][132] f32 = 35,904  (dinv-premultiplied)
#define L_Y1H  35904    // 10,240 : 5 tiles x 16 x 64
#define L_Y1L  46144    // 10,240 (ends 56,384; dead before Y2 written)
#define L_Y2H  49152    // 16,384 : 4 tiles x 16 x 128
#define L_Y2L  65536    // 16,384 (ends 81,920)
#define L_X2   0        // [50][132] f32 = 26,400  (dinv-premultiplied)
#define L_Y3H  26400    // 8,192 : 2 tiles x 16 x 128
#define L_Y3L  34592    // 8,192 (ends 42,784)
#define L_POOL 42784    // 512

#define MFMA3(d, ah, al, wh, wl)                                        \
    d = __builtin_amdgcn_mfma_f32_16x16x32_bf16(ah, wh, d, 0, 0, 0);    \
    d = __builtin_amdgcn_mfma_f32_16x16x32_bf16(ah, wl, d, 0, 0, 0);    \
    d = __builtin_amdgcn_mfma_f32_16x16x32_bf16(al, wh, d, 0, 0, 0);

// ---------------------------------------------------------------------------
__device__ __forceinline__ void split_bf16(float w, ushort_t* hp, ushort_t* lp) {
    __hip_bfloat16 hb = __float2bfloat16(w);
    float hf = __bfloat162float(hb);
    __hip_bfloat16 lb = __float2bfloat16(w - hf);
    *hp = *(ushort_t*)&hb;
    *lp = *(ushort_t*)&lb;
}

__device__ __forceinline__ float dinv_of(int ri) {
    if (ri < 0 || ri >= NN) return 0.f;
    int lo = ri - 9; if (lo < 0) lo = 0;
    int hi = ri + 9; if (hi > NN - 1) hi = NN - 1;
    return 1.0f / sqrtf((float)(hi - lo + 1));
}

// fragment element offset within [tiles][16 rows][K] plane; tile size = 16*K
__device__ __forceinline__ int frag_off(int r, int k, int K16) {
    return (r >> 4) * K16 + (k >> 5) * 512 + ((k >> 3) & 3) * 128
         + (r & 15) * 8 + (k & 7);
}

// ---------------------------------------------------------------------------
// fused: full 3-layer GCN chain for one (32-row tile, batch) in LDS.
// Row frames: Y1/X1 lr1: gr = r0-18+lr1 (0..67)
//             Y2/X2 lr2: gr = r0-9+lr2  (0..49)
//             Y3     lr3: gr = r0+lr3   (0..31)
// Max live accumulators: acc1 48 / acc2 32 + acc3 16 regs (no spill by design)
// ---------------------------------------------------------------------------
__global__ __launch_bounds__(256, 2) void fused(
    const float* __restrict__ Lm, const ushort_t* __restrict__ wext,
    const float* __restrict__ We, const float* __restrict__ be,
    const float* __restrict__ b1, const float* __restrict__ b2,
    const float* __restrict__ b3, float* __restrict__ partial)
{
    __shared__ __align__(16) char lds[81920];
    float*    X1  = (float*)(lds + L_X1);
    ushort_t* Y1h = (ushort_t*)(lds + L_Y1H);
    ushort_t* Y1l = (ushort_t*)(lds + L_Y1L);
    ushort_t* Y2h = (ushort_t*)(lds + L_Y2H);
    ushort_t* Y2l = (ushort_t*)(lds + L_Y2L);
    float*    X2  = (float*)(lds + L_X2);
    ushort_t* Y3h = (ushort_t*)(lds + L_Y3H);
    ushort_t* Y3l = (ushort_t*)(lds + L_Y3L);
    float*    pool = (float*)(lds + L_POOL);

    const int tid  = threadIdx.x;
    const int lane = tid & 63;
    const int wave = tid >> 6;
    const int wm = wave & 1, wn = wave >> 1;
    const int l15 = lane & 15, lg = lane >> 4;
    const int rt = blockIdx.x, b = blockIdx.y;
    const int r0 = rt * 32;

    // ================= band1 (encoder fused) -> Y1 [68 rows][64] ==========
    {
        const int c = tid & 63, s = tid >> 6;     // 4 slices x 17 rows
        const float w0 = We[c], w1 = We[64+c], w2 = We[128+c], bk = be[c];
        const float* Xb = Lm + (size_t)b * (NN * 3);
        const int base = r0 - 27 + s * 17;
        float z[35];
        #pragma unroll
        for (int j = 0; j < 35; ++j) {
            int gr = base + j;
            float v = 0.f;
            if (gr >= 0 && gr < NN)
                v = (bk + Xb[gr*3]*w0 + Xb[gr*3+1]*w1 + Xb[gr*3+2]*w2)
                    * dinv_of(gr);
            z[j] = v;
        }
        float ws = 0.f;
        #pragma unroll
        for (int j = 0; j < 19; ++j) ws += z[j];
        #pragma unroll
        for (int rr = 0; rr < 17; ++rr) {
            if (rr) ws += z[rr + 18] - z[rr - 1];
            int lr = s * 17 + rr;
            float y = ws * dinv_of(r0 - 18 + lr);
            int off = frag_off(lr, c, 1024);
            split_bf16(y, Y1h + off, Y1l + off);
        }
        for (int idx = tid; idx < 768; idx += 256) {   // zero pad rows 68..79
            int lr = 68 + (idx >> 6), cc = idx & 63;
            int off = frag_off(lr, cc, 1024);
            Y1h[off] = 0; Y1l[off] = 0;
        }
    }
    __syncthreads();

    // ================= GEMM1 (K=64, N=128) + epi -> X1 (dinv-premult) ======
    {
        f32x4 acc[3][4] = {};
        #pragma unroll
        for (int kt = 0; kt < 2; ++kt) {
            bf16x8 a[3][2];
            #pragma unroll
            for (int mt = 0; mt < 3; ++mt) {
                int off = (wm*2 + mt) * 1024 + kt * 512 + lane * 8;
                a[mt][0] = *(const bf16x8*)(Y1h + off);
                a[mt][1] = *(const bf16x8*)(Y1l + off);
            }
            #pragma unroll
            for (int nt = 0; nt < 4; ++nt) {
                int woff = (wn*4 + nt) * 1024 + kt * 512 + lane * 8;
                bf16x8 wh = *(const bf16x8*)(wext + W1H + woff);
                bf16x8 wl = *(const bf16x8*)(wext + W1L + woff);
                #pragma unroll
                for (int mt = 0; mt < 3; ++mt) {
                    MFMA3(acc[mt][nt], a[mt][0], a[mt][1], wh, wl);
                }
            }
        }
        #pragma unroll
        for (int mt = 0; mt < 3; ++mt) {
            int t = wm*2 + mt;
            #pragma unroll
            for (int nt = 0; nt < 4; ++nt) {
                int cl = wn*64 + nt*16 + l15;
                float bv = b1[cl];
                #pragma unroll
                for (int r = 0; r < 4; ++r) {
                    int lr = t*16 + lg*4 + r;
                    if (lr < 68)
                        X1[lr*132 + cl] =
                            dinv_of(r0 - 18 + lr) * fmaxf(acc[mt][nt][r] + bv, 0.f);
                }
            }
        }
    }
    __syncthreads();

    // ================= band2: X1 -> Y2 [50 rows][128] ======================
    {
        const int c = tid & 127, h = tid >> 7;    // 2 groups x 25 rows
        const int L0 = h * 25;
        float ws = 0.f;
        #pragma unroll
        for (int j = 0; j < 19; ++j) ws += X1[(L0 + j)*132 + c];
        #pragma unroll
        for (int rr = 0; rr < 25; ++rr) {
            int lr = L0 + rr;
            if (rr) ws += X1[(lr + 18)*132 + c] - X1[(lr - 1)*132 + c];
            float y = ws * dinv_of(r0 - 9 + lr);
            int off = frag_off(lr, c, 2048);
            split_bf16(y, Y2h + off, Y2l + off);
        }
        for (int idx = tid; idx < 1792; idx += 256) {  // zero pad rows 50..63
            int lr = 50 + idx / 128, cc = idx & 127;
            int off = frag_off(lr, cc, 2048);
            Y2h[off] = 0; Y2l[off] = 0;
        }
    }
    __syncthreads();

    // ===== nc loop: GEMM2 n-chunk -> X2 -> band3 -> Y3 -> GEMM3 partial ====
    f32x4 acc3[4] = {};
    #pragma unroll
    for (int nc = 0; nc < 2; ++nc) {
        {   // GEMM2 chunk (K=128, N-chunk=128)
            f32x4 acc2[2][4] = {};
            #pragma unroll
            for (int kt = 0; kt < 4; ++kt) {
                bf16x8 a[2][2];
                #pragma unroll
                for (int mt = 0; mt < 2; ++mt) {
                    int off = (wm*2 + mt) * 2048 + kt * 512 + lane * 8;
                    a[mt][0] = *(const bf16x8*)(Y2h + off);
                    a[mt][1] = *(const bf16x8*)(Y2l + off);
                }
                #pragma unroll
                for (int nt = 0; nt < 4; ++nt) {
                    int woff = (nc*8 + wn*4 + nt) * 2048 + kt * 512 + lane * 8;
                    bf16x8 wh = *(const bf16x8*)(wext + W2H + woff);
                    bf16x8 wl = *(const bf16x8*)(wext + W2L + woff);
                    #pragma unroll
                    for (int mt = 0; mt < 2; ++mt) {
                        MFMA3(acc2[mt][nt], a[mt][0], a[mt][1], wh, wl);
                    }
                }
            }
            // epi2 -> X2 (dinv-premultiplied)
            #pragma unroll
            for (int mt = 0; mt < 2; ++mt)
            #pragma unroll
            for (int nt = 0; nt < 4; ++nt) {
                int cl = wn*64 + nt*16 + l15;
                float bv = b2[nc*128 + cl];
                #pragma unroll
                for (int r = 0; r < 4; ++r) {
                    int lr = (wm*2 + mt)*16 + lg*4 + r;
                    if (lr < 50)
                        X2[lr*132 + cl] =
                            dinv_of(r0 - 9 + lr) * fmaxf(acc2[mt][nt][r] + bv, 0.f);
                }
            }
        }
        __syncthreads();

        {   // band3: X2 -> Y3 [32 rows][128 local k]
            const int c = tid & 127, h = tid >> 7;    // 2 groups x 16 rows
            const int L0 = h * 16;
            float ws = 0.f;
            #pragma unroll
            for (int j = 0; j < 19; ++j) ws += X2[(L0 + j)*132 + c];
            #pragma unroll
            for (int rr = 0; rr < 16; ++rr) {
                int lr = L0 + rr;
                if (rr) ws += X2[(lr + 18)*132 + c] - X2[(lr - 1)*132 + c];
                float y = ws * dinv_of(r0 + lr);
                int off = frag_off(lr, c, 2048);
                split_bf16(y, Y3h + off, Y3l + off);
            }
        }
        __syncthreads();

        // GEMM3 partial (M=2 tiles, N=128, K-chunk=128)
        #pragma unroll
        for (int kt = 0; kt < 4; ++kt) {
            int aoff = wm * 2048 + kt * 512 + lane * 8;
            bf16x8 a0 = *(const bf16x8*)(Y3h + aoff);
            bf16x8 a1 = *(const bf16x8*)(Y3l + aoff);
            #pragma unroll
            for (int nt = 0; nt < 4; ++nt) {
                int woff = (wn*4 + nt) * 4096 + (nc*4 + kt) * 512 + lane * 8;
                bf16x8 wh = *(const bf16x8*)(wext + W3H + woff);
                bf16x8 wl = *(const bf16x8*)(wext + W3L + woff);
                MFMA3(acc3[nt], a0, a1, wh, wl);
            }
        }
        __syncthreads();   // WAR: next nc overwrites X2/Y3
    }

    // ================= pool: column sums of relu(acc3 + b3) ================
    if (tid < 128) pool[tid] = 0.f;
    __syncthreads();
    #pragma unroll
    for (int nt = 0; nt < 4; ++nt) {
        float bv = b3[wn*64 + nt*16 + l15];
        float cs = 0.f;
        #pragma unroll
        for (int r = 0; r < 4; ++r) {
            int gr = r0 + wm*16 + lg*4 + r;
            if (gr < NN) cs += fmaxf(acc3[nt][r] + bv, 0.f);
        }
        cs += __shfl_xor(cs, 16);
        cs += __shfl_xor(cs, 32);
        if (lane < 16) atomicAdd(&pool[wn*64 + nt*16 + lane], cs);
    }
    __syncthreads();
    if (tid < 128) partial[((size_t)b * 15 + rt) * 128 + tid] = pool[tid];
}

// ---------------------------------------------------------------------------
// wconv: W fp32 [K][N] -> bf16 hi/lo planes in fragment layout
// ---------------------------------------------------------------------------
__global__ __launch_bounds__(256) void wconv(
    const float* __restrict__ W1, const float* __restrict__ W2,
    const float* __restrict__ W3, ushort_t* __restrict__ wext)
{
    int i = blockIdx.x * 256 + threadIdx.x;
    float w; int off_h, off_l, idx;
    if (i < 8192) {                       // W1: K=64,  N=128
        int k = i >> 7, n = i & 127;
        w = W1[i]; idx = frag_off(n, k, 1024);  off_h = W1H; off_l = W1L;
    } else if (i < 40960) {               // W2: K=128, N=256
        int j = i - 8192;
        int k = j >> 8, n = j & 255;
        w = W2[j]; idx = frag_off(n, k, 2048);  off_h = W2H; off_l = W2L;
    } else if (i < 73728) {               // W3: K=256, N=128
        int j = i - 40960;
        int k = j >> 7, n = j & 127;
        w = W3[j]; idx = frag_off(n, k, 4096);  off_h = W3H; off_l = W3L;
    } else return;
    split_bf16(w, wext + off_h + idx, wext + off_l + idx);
}

// ---------------------------------------------------------------------------
// head: gf = mean-pool reduce; features = relu(gf@Wf+bf); out = feats@Wc+bc
// ---------------------------------------------------------------------------
__global__ __launch_bounds__(512) void head_kernel(
    const float* __restrict__ partial, const float* __restrict__ Wf,
    const float* __restrict__ bf, const float* __restrict__ Wc,
    const float* __restrict__ bc, float* __restrict__ dout)
{
    __shared__ float gfs[128];
    __shared__ float feats[512];
    int b = blockIdx.x, t = threadIdx.x;
    if (t < 128) {
        const float* p = partial + (size_t)b * (15 * 128);
        float s = 0.f;
        #pragma unroll
        for (int tt = 0; tt < 15; ++tt) s += p[tt * 128 + t];
        s *= (1.0f / 468.0f);
        gfs[t] = s;
        dout[65792 + b * 128 + t] = s;       // graph_features
    }
    __syncthreads();
    float a = bf[t];
    for (int k = 0; k < 128; ++k) a += gfs[k] * Wf[k * 512 + t];
    a = fmaxf(a, 0.f);
    dout[256 + b * 512 + t] = a;             // features
    feats[t] = a;
    __syncthreads();
    if (t < 64) {
        float s0 = 0.f, s1 = 0.f;
        for (int c = t; c < 512; c += 64) {
            float f = feats[c];
            s0 += f * Wc[c * 2 + 0];
            s1 += f * Wc[c * 2 + 1];
        }
        #pragma unroll
        for (int off = 32; off; off >>= 1) {
            s0 += __shfl_down(s0, off);
            s1 += __shfl_down(s1, off);
        }
        if (t == 0) {
            dout[b * 2 + 0] = s0 + bc[0];
            dout[b * 2 + 1] = s1 + bc[1];
        }
    }
}

// ---------------------------------------------------------------------------
extern "C" void kernel_launch(void* const* d_in, const int* in_sizes, int n_in,
                              void* d_out, int out_size, void* d_ws, size_t ws_size,
                              hipStream_t stream)
{
    const float* landmarks = (const float*)d_in[0];
    const float* W_enc     = (const float*)d_in[1];
    const float* b_enc     = (const float*)d_in[2];
    const float* W1        = (const float*)d_in[3];
    const float* b1        = (const float*)d_in[4];
    const float* W2        = (const float*)d_in[5];
    const float* b2        = (const float*)d_in[6];
    const float* W3        = (const float*)d_in[7];
    const float* b3        = (const float*)d_in[8];
    const float* W_fus     = (const float*)d_in[9];
    const float* b_fus     = (const float*)d_in[10];
    const float* W_cls     = (const float*)d_in[11];
    const float* b_cls     = (const float*)d_in[12];
    float* out = (float*)d_out;

    char* ws = (char*)d_ws;
    ushort_t* wext = (ushort_t*)(ws + 0);        // 294,912 B
    float* partial = (float*)(ws + 294912);      // 983,040 B

    wconv<<<288, 256, 0, stream>>>(W1, W2, W3, wext);
    fused<<<dim3(15, 128), 256, 0, stream>>>(
        landmarks, wext, W_enc, b_enc, b1, b2, b3, partial);
    head_kernel<<<128, 512, 0, stream>>>(partial, W_fus, b_fus, W_cls, b_cls, out);
}

// Round 9
// 104.723 us; speedup vs baseline: 5.8535x; 2.0490x over previous
//
#include <hip/hip_runtime.h>
#include <hip/hip_bf16.h>

typedef __bf16 bf16x8 __attribute__((ext_vector_type(8)));
typedef float  f32x4  __attribute__((ext_vector_type(4)));
typedef unsigned short ushort_t;

#define NN 468

// wext element offsets (ushort), fragment-major planes (NOT swizzled)
#define W1H 0
#define W1L 8192
#define W2H 16384
#define W2L 49152
#define W3H 81920
#define W3L 114688

// LDS byte offsets (80 KB exactly -> 2 blocks/CU)
#define L_X0   0        // [86][68] f32 = 23392          (phase A)
#define L_LM   23392    // 258 f32 = 1032                (phase A)
#define L_X1   0        // [68][132] f32 = 35904         (phase B,C)
#define L_X2   0        // [50][132] f32 = 26400         (phase D)
#define L_Y3   26400    // 2 planes x 2048 ushort = 8192 (phase D, k-chunked)
#define L_Y2   35904    // 2 planes x 8192 ushort = 32768 (C,D)
#define L_Y1   60416    // 2 planes x 5120 ushort = 20480 (A,B)
#define L_DTAB 80896    // 86 f32
#define L_POOL 81280    // 128 f32

#define MFMA3(d, ah, al, wh, wl)                                        \
    d = __builtin_amdgcn_mfma_f32_16x16x32_bf16(ah, wh, d, 0, 0, 0);    \
    d = __builtin_amdgcn_mfma_f32_16x16x32_bf16(ah, wl, d, 0, 0, 0);    \
    d = __builtin_amdgcn_mfma_f32_16x16x32_bf16(al, wh, d, 0, 0, 0);

// ---------------------------------------------------------------------------
__device__ __forceinline__ void split_bf16(float w, ushort_t* hp, ushort_t* lp) {
    __hip_bfloat16 hb = __float2bfloat16(w);
    float hf = __bfloat162float(hb);
    __hip_bfloat16 lb = __float2bfloat16(w - hf);
    *hp = *(ushort_t*)&hb;
    *lp = *(ushort_t*)&lb;
}

// pack 4 split values, write hi/lo as one b64 each (dst 8B-aligned)
__device__ __forceinline__ void pack_split4(const float* y,
                                            ushort_t* hdst, ushort_t* ldst) {
    ushort_t h[4], l[4];
    #pragma unroll
    for (int j = 0; j < 4; ++j) {
        __hip_bfloat16 hb = __float2bfloat16(y[j]);
        float hf = __bfloat162float(hb);
        __hip_bfloat16 lb = __float2bfloat16(y[j] - hf);
        h[j] = *(ushort_t*)&hb; l[j] = *(ushort_t*)&lb;
    }
    uint2 hv = make_uint2((unsigned)h[0] | ((unsigned)h[1] << 16),
                          (unsigned)h[2] | ((unsigned)h[3] << 16));
    uint2 lv = make_uint2((unsigned)l[0] | ((unsigned)l[1] << 16),
                          (unsigned)l[2] | ((unsigned)l[3] << 16));
    *(uint2*)hdst = hv;
    *(uint2*)ldst = lv;
}

// unswizzled fragment offset (used for W planes in global memory)
__device__ __forceinline__ int frag_off(int r, int k, int K16) {
    return (r >> 4) * K16 + (k >> 5) * 512 + ((k >> 3) & 3) * 128
         + (r & 15) * 8 + (k & 7);
}

// swizzled Y-plane offset (LDS): unit' = q*16 + ((r ^ 2q) & 15)
__device__ __forceinline__ int ywoff(int r, int k4, int K16) {
    int q = (k4 >> 3) & 3;
    int u = q * 16 + (((r & 15) ^ (q << 1)) & 15);
    return (r >> 4) * K16 + (k4 >> 5) * 512 + u * 8 + (k4 & 7);
}

// ---------------------------------------------------------------------------
// fused: full 3-layer GCN chain for one (32-row tile, batch) in LDS.
// All X tensors stored dinv-premultiplied fp32; all Y tensors bf16 hi/lo in
// swizzled fragment layout. dinv values from per-block LDS table.
// ---------------------------------------------------------------------------
__global__ __launch_bounds__(256, 2) void fused(
    const float* __restrict__ Lm, const ushort_t* __restrict__ wext,
    const float* __restrict__ We, const float* __restrict__ be,
    const float* __restrict__ b1, const float* __restrict__ b2,
    const float* __restrict__ b3, float* __restrict__ partial)
{
    __shared__ __align__(16) char lds[81920];
    float*    X0   = (float*)(lds + L_X0);
    float*    lmst = (float*)(lds + L_LM);
    float*    X1   = (float*)(lds + L_X1);
    float*    X2   = (float*)(lds + L_X2);
    ushort_t* Y3h  = (ushort_t*)(lds + L_Y3);  ushort_t* Y3l = Y3h + 2048;
    ushort_t* Y2h  = (ushort_t*)(lds + L_Y2);  ushort_t* Y2l = Y2h + 8192;
    ushort_t* Y1h  = (ushort_t*)(lds + L_Y1);  ushort_t* Y1l = Y1h + 5120;
    float*    dtab = (float*)(lds + L_DTAB);
    float*    pool = (float*)(lds + L_POOL);

    const int tid  = threadIdx.x;
    const int lane = tid & 63;
    const int wave = tid >> 6;
    const int wm = wave & 1, wn = wave >> 1;
    const int l15 = lane & 15, lg = lane >> 4;
    // swizzled lane index for A-fragment reads (matches ywoff)
    const int lswz = (lane & 48) + (((lane & 15) ^ ((lane >> 4) << 1)) & 15);
    const int rt = blockIdx.x, b = blockIdx.y;
    const int r0 = rt * 32;

    // ---------------- stage: dinv table, landmarks, pool init -------------
    if (tid < 86) {
        int ri = r0 - 27 + tid;
        float dv = 0.f;
        if (ri >= 0 && ri < NN) {
            int lo = ri - 9; if (lo < 0) lo = 0;
            int hi = ri + 9; if (hi > NN - 1) hi = NN - 1;
            dv = 1.0f / sqrtf((float)(hi - lo + 1));
        }
        dtab[tid] = dv;
    }
    if (tid < 258) {
        int g = (r0 - 27) * 3 + tid;
        lmst[tid] = (g >= 0 && g < NN * 3) ? Lm[(size_t)b * (NN * 3) + g] : 0.f;
    }
    if (tid < 128) pool[tid] = 0.f;
    __syncthreads();

    // ---------------- encode: X0[86][68] = enc(row) * dinv -----------------
    {
        const int c = tid & 63;
        const float w0 = We[c], w1 = We[64 + c], w2 = We[128 + c], bk = be[c];
        for (int g = tid >> 6; g < 86; g += 4) {
            float x = bk + lmst[g*3]*w0 + lmst[g*3+1]*w1 + lmst[g*3+2]*w2;
            X0[g * 68 + c] = x * dtab[g];
        }
    }
    __syncthreads();

    // ---------------- band1: X0 -> Y1 (68 rows x 64), pad 68..79 -----------
    {
        const int c4 = (tid & 15) << 2;
        const int lr = (tid >> 4) * 5;             // 16 groups x 5 rows
        f32x4 ws = {};
        #pragma unroll
        for (int d = 0; d < 19; ++d)
            ws += *(const f32x4*)(X0 + (lr + d) * 68 + c4);
        #pragma unroll
        for (int rr = 0; rr < 5; ++rr) {
            if (rr) ws += *(const f32x4*)(X0 + (lr + rr + 18) * 68 + c4)
                        - *(const f32x4*)(X0 + (lr + rr - 1)  * 68 + c4);
            int row = lr + rr;
            if (row < 68) {
                float dv = dtab[row + 9];
                float y4[4] = {ws[0]*dv, ws[1]*dv, ws[2]*dv, ws[3]*dv};
                int off = ywoff(row, c4, 1024);
                pack_split4(y4, Y1h + off, Y1l + off);
            }
        }
        for (int e = tid; e < 192; e += 256) {     // zero rows 68..79
            int off = ywoff(68 + (e >> 4), (e & 15) << 2, 1024);
            *(uint2*)(Y1h + off) = make_uint2(0, 0);
            *(uint2*)(Y1l + off) = make_uint2(0, 0);
        }
    }
    __syncthreads();

    // ---------------- GEMM1: Y1(5 tiles) @ W1 -> X1[68][132] premult -------
    {
        f32x4 acc[3][4] = {};
        #pragma unroll
        for (int kt = 0; kt < 2; ++kt) {
            bf16x8 a[3][2];
            #pragma unroll
            for (int mt = 0; mt < 3; ++mt) {
                int off = (wm*2 + mt) * 1024 + kt * 512 + lswz * 8;
                a[mt][0] = *(const bf16x8*)(Y1h + off);
                a[mt][1] = *(const bf16x8*)(Y1l + off);
            }
            #pragma unroll
            for (int nt = 0; nt < 4; ++nt) {
                int woff = (wn*4 + nt) * 1024 + kt * 512 + lane * 8;
                bf16x8 wh = *(const bf16x8*)(wext + W1H + woff);
                bf16x8 wl = *(const bf16x8*)(wext + W1L + woff);
                #pragma unroll
                for (int mt = 0; mt < 3; ++mt) {
                    MFMA3(acc[mt][nt], a[mt][0], a[mt][1], wh, wl);
                }
            }
        }
        #pragma unroll
        for (int mt = 0; mt < 3; ++mt)
        #pragma unroll
        for (int nt = 0; nt < 4; ++nt) {
            int cl = wn*64 + nt*16 + l15;
            float bv = b1[cl];
            #pragma unroll
            for (int r = 0; r < 4; ++r) {
                int lr = (wm*2 + mt)*16 + lg*4 + r;
                if (lr < 68)
                    X1[lr*132 + cl] = dtab[lr + 9] * fmaxf(acc[mt][nt][r] + bv, 0.f);
            }
        }
    }
    __syncthreads();

    // ---------------- band2: X1 -> Y2 (50 rows x 128), pad 50..63 ----------
    {
        const int c4 = (tid & 31) << 2;
        const int lr = (tid >> 5) * 7;             // 8 groups x 7 rows
        f32x4 ws = {};
        #pragma unroll
        for (int d = 0; d < 19; ++d)
            ws += *(const f32x4*)(X1 + (lr + d) * 132 + c4);
        #pragma unroll
        for (int rr = 0; rr < 7; ++rr) {
            if (rr) ws += *(const f32x4*)(X1 + (lr + rr + 18) * 132 + c4)
                        - *(const f32x4*)(X1 + (lr + rr - 1)  * 132 + c4);
            int row = lr + rr;
            if (row < 50) {
                float dv = dtab[row + 18];
                float y4[4] = {ws[0]*dv, ws[1]*dv, ws[2]*dv, ws[3]*dv};
                int off = ywoff(row, c4, 2048);
                pack_split4(y4, Y2h + off, Y2l + off);
            }
        }
        for (int e = tid; e < 448; e += 256) {     // zero rows 50..63
            int off = ywoff(50 + (e >> 5), (e & 31) << 2, 2048);
            *(uint2*)(Y2h + off) = make_uint2(0, 0);
            *(uint2*)(Y2l + off) = make_uint2(0, 0);
        }
    }
    __syncthreads();

    // ------- nc loop: GEMM2 -> X2; ncc loop: band3 -> Y3 -> GEMM3 ----------
    f32x4 acc3[4] = {};
    #pragma unroll
    for (int nc = 0; nc < 2; ++nc) {
        {
            f32x4 acc2[2][4] = {};
            #pragma unroll
            for (int kt = 0; kt < 4; ++kt) {
                bf16x8 a[2][2];
                #pragma unroll
                for (int mt = 0; mt < 2; ++mt) {
                    int off = (wm*2 + mt) * 2048 + kt * 512 + lswz * 8;
                    a[mt][0] = *(const bf16x8*)(Y2h + off);
                    a[mt][1] = *(const bf16x8*)(Y2l + off);
                }
                #pragma unroll
                for (int nt = 0; nt < 4; ++nt) {
                    int woff = (nc*8 + wn*4 + nt) * 2048 + kt * 512 + lane * 8;
                    bf16x8 wh = *(const bf16x8*)(wext + W2H + woff);
                    bf16x8 wl = *(const bf16x8*)(wext + W2L + woff);
                    #pragma unroll
                    for (int mt = 0; mt < 2; ++mt) {
                        MFMA3(acc2[mt][nt], a[mt][0], a[mt][1], wh, wl);
                    }
                }
            }
            // epi2 -> X2 premult (X1 readers finished at band2's barrier)
            #pragma unroll
            for (int mt = 0; mt < 2; ++mt)
            #pragma unroll
            for (int nt = 0; nt < 4; ++nt) {
                int cl = wn*64 + nt*16 + l15;
                float bv = b2[nc*128 + cl];
                #pragma unroll
                for (int r = 0; r < 4; ++r) {
                    int lr = (wm*2 + mt)*16 + lg*4 + r;
                    if (lr < 50)
                        X2[lr*132 + cl] =
                            dtab[lr + 18] * fmaxf(acc2[mt][nt][r] + bv, 0.f);
                }
            }
        }
        __syncthreads();

        #pragma unroll
        for (int ncc = 0; ncc < 2; ++ncc) {
            {   // band3: X2 cols [ncc*64,+64) -> Y3 [32 rows][64]
                const int c4 = (tid & 15) << 2;
                const int lr = (tid >> 4) * 2;     // 16 groups x 2 rows
                f32x4 ws = {};
                #pragma unroll
                for (int d = 0; d < 19; ++d)
                    ws += *(const f32x4*)(X2 + (lr + d) * 132 + ncc*64 + c4);
                #pragma unroll
                for (int rr = 0; rr < 2; ++rr) {
                    if (rr) ws += *(const f32x4*)(X2 + (lr+rr+18)*132 + ncc*64 + c4)
                                - *(const f32x4*)(X2 + (lr+rr-1) *132 + ncc*64 + c4);
                    int row = lr + rr;
                    float dv = dtab[row + 27];
                    float y4[4] = {ws[0]*dv, ws[1]*dv, ws[2]*dv, ws[3]*dv};
                    int off = ywoff(row, c4, 1024);
                    pack_split4(y4, Y3h + off, Y3l + off);
                }
            }
            __syncthreads();

            // GEMM3 partial (Y3 k-chunk = 64)
            #pragma unroll
            for (int kt = 0; kt < 2; ++kt) {
                int aoff = wm * 1024 + kt * 512 + lswz * 8;
                bf16x8 a0 = *(const bf16x8*)(Y3h + aoff);
                bf16x8 a1 = *(const bf16x8*)(Y3l + aoff);
                #pragma unroll
                for (int nt = 0; nt < 4; ++nt) {
                    int wkt = nc*4 + ncc*2 + kt;
                    int woff = (wn*4 + nt) * 4096 + wkt * 512 + lane * 8;
                    bf16x8 wh = *(const bf16x8*)(wext + W3H + woff);
                    bf16x8 wl = *(const bf16x8*)(wext + W3L + woff);
                    MFMA3(acc3[nt], a0, a1, wh, wl);
                }
            }
            __syncthreads();   // Y3 reads done before next band3/epi2
        }
    }

    // ---------------- pool: column sums of relu(acc3 + b3) -----------------
    #pragma unroll
    for (int nt = 0; nt < 4; ++nt) {
        float bv = b3[wn*64 + nt*16 + l15];
        float cs = 0.f;
        #pragma unroll
        for (int r = 0; r < 4; ++r) {
            int gr = r0 + wm*16 + lg*4 + r;
            if (gr < NN) cs += fmaxf(acc3[nt][r] + bv, 0.f);
        }
        cs += __shfl_xor(cs, 16);
        cs += __shfl_xor(cs, 32);
        if (lane < 16) atomicAdd(&pool[wn*64 + nt*16 + lane], cs);
    }
    __syncthreads();
    if (tid < 128) partial[((size_t)b * 15 + rt) * 128 + tid] = pool[tid];
}

// ---------------------------------------------------------------------------
// wconv: W fp32 [K][N] -> bf16 hi/lo planes, fragment layout (unswizzled)
// ---------------------------------------------------------------------------
__global__ __launch_bounds__(256) void wconv(
    const float* __restrict__ W1, const float* __restrict__ W2,
    const float* __restrict__ W3, ushort_t* __restrict__ wext)
{
    int i = blockIdx.x * 256 + threadIdx.x;
    float w; int off_h, off_l, idx;
    if (i < 8192) {                       // W1: K=64,  N=128
        int k = i >> 7, n = i & 127;
        w = W1[i]; idx = frag_off(n, k, 1024);  off_h = W1H; off_l = W1L;
    } else if (i < 40960) {               // W2: K=128, N=256
        int j = i - 8192;
        int k = j >> 8, n = j & 255;
        w = W2[j]; idx = frag_off(n, k, 2048);  off_h = W2H; off_l = W2L;
    } else if (i < 73728) {               // W3: K=256, N=128
        int j = i - 40960;
        int k = j >> 7, n = j & 127;
        w = W3[j]; idx = frag_off(n, k, 4096);  off_h = W3H; off_l = W3L;
    } else return;
    split_bf16(w, wext + off_h + idx, wext + off_l + idx);
}

// ---------------------------------------------------------------------------
// head: gf = mean-pool reduce; features = relu(gf@Wf+bf); out = feats@Wc+bc
// ---------------------------------------------------------------------------
__global__ __launch_bounds__(512) void head_kernel(
    const float* __restrict__ partial, const float* __restrict__ Wf,
    const float* __restrict__ bf, const float* __restrict__ Wc,
    const float* __restrict__ bc, float* __restrict__ dout)
{
    __shared__ float gfs[128];
    __shared__ float feats[512];
    int b = blockIdx.x, t = threadIdx.x;
    if (t < 128) {
        const float* p = partial + (size_t)b * (15 * 128);
        float s = 0.f;
        #pragma unroll
        for (int tt = 0; tt < 15; ++tt) s += p[tt * 128 + t];
        s *= (1.0f / 468.0f);
        gfs[t] = s;
        dout[65792 + b * 128 + t] = s;       // graph_features
    }
    __syncthreads();
    float a = bf[t];
    for (int k = 0; k < 128; ++k) a += gfs[k] * Wf[k * 512 + t];
    a = fmaxf(a, 0.f);
    dout[256 + b * 512 + t] = a;             // features
    feats[t] = a;
    __syncthreads();
    if (t < 64) {
        float s0 = 0.f, s1 = 0.f;
        for (int c = t; c < 512; c += 64) {
            float f = feats[c];
            s0 += f * Wc[c * 2 + 0];
            s1 += f * Wc[c * 2 + 1];
        }
        #pragma unroll
        for (int off = 32; off; off >>= 1) {
            s0 += __shfl_down(s0, off);
            s1 += __shfl_down(s1, off);
        }
        if (t == 0) {
            dout[b * 2 + 0] = s0 + bc[0];
            dout[b * 2 + 1] = s1 + bc[1];
        }
    }
}

// ---------------------------------------------------------------------------
extern "C" void kernel_launch(void* const* d_in, const int* in_sizes, int n_in,
                              void* d_out, int out_size, void* d_ws, size_t ws_size,
                              hipStream_t stream)
{
    const float* landmarks = (const float*)d_in[0];
    const float* W_enc     = (const float*)d_in[1];
    const float* b_enc     = (const float*)d_in[2];
    const float* W1        = (const float*)d_in[3];
    const float* b1        = (const float*)d_in[4];
    const float* W2        = (const float*)d_in[5];
    const float* b2        = (const float*)d_in[6];
    const float* W3        = (const float*)d_in[7];
    const float* b3        = (const float*)d_in[8];
    const float* W_fus     = (const float*)d_in[9];
    const float* b_fus     = (const float*)d_in[10];
    const float* W_cls     = (const float*)d_in[11];
    const float* b_cls     = (const float*)d_in[12];
    float* out = (float*)d_out;

    char* ws = (char*)d_ws;
    ushort_t* wext = (ushort_t*)(ws + 0);        // 294,912 B
    float* partial = (float*)(ws + 294912);      // 983,040 B

    wconv<<<288, 256, 0, stream>>>(W1, W2, W3, wext);
    fused<<<dim3(15, 128), 256, 0, stream>>>(
        landmarks, wext, W_enc, b_enc, b1, b2, b3, partial);
    head_kernel<<<128, 512, 0, stream>>>(partial, W_fus, b_fus, W_cls, b_cls, out);
}

// Round 10
// 102.234 us; speedup vs baseline: 5.9959x; 1.0243x over previous
//
#include <hip/hip_runtime.h>
#include <hip/hip_bf16.h>

typedef __bf16 bf16x8 __attribute__((ext_vector_type(8)));
typedef float  f32x4  __attribute__((ext_vector_type(4)));
typedef unsigned short ushort_t;

#define NN 468

// wext element offsets (ushort), fragment-major planes (NOT swizzled)
#define W1H 0
#define W1L 8192
#define W2H 16384
#define W2L 49152
#define W3H 81920
#define W3L 114688

// LDS byte offsets (53,248 B total -> 3 blocks/CU)
#define L_X0   0        // [86][68] f32 = 23392            (phase A)
#define L_LM   23392    // 258 f32 = 1032                  (phase A)
#define L_Y1   24424    // 2 planes x 5120 ushort = 20480  (A..GEMM1; ends 44904)
#define L_X1   0        // [68][132] f32 = 35904           (epi1..band2)
#define L_Y2   35904    // 2 planes x 4096 ushort = 16384  (band2/GEMM2 k-chunk; ends 52288)
#define L_X2   0        // [50][132] f32 = 26400           (phase D)
#define L_Y3   26400    // 2 planes x 2048 ushort = 8192   (phase D; ends 34592)
#define L_DTAB 52288    // 86 f32 = 344
#define L_POOL 52632    // 128 f32 = 512   (ends 53144)

#define MFMA3(d, ah, al, wh, wl)                                        \
    d = __builtin_amdgcn_mfma_f32_16x16x32_bf16(ah, wh, d, 0, 0, 0);    \
    d = __builtin_amdgcn_mfma_f32_16x16x32_bf16(ah, wl, d, 0, 0, 0);    \
    d = __builtin_amdgcn_mfma_f32_16x16x32_bf16(al, wh, d, 0, 0, 0);

// ---------------------------------------------------------------------------
__device__ __forceinline__ void split_bf16(float w, ushort_t* hp, ushort_t* lp) {
    __hip_bfloat16 hb = __float2bfloat16(w);
    float hf = __bfloat162float(hb);
    __hip_bfloat16 lb = __float2bfloat16(w - hf);
    *hp = *(ushort_t*)&hb;
    *lp = *(ushort_t*)&lp[0] == 0 ? *(ushort_t*)&lb : *(ushort_t*)&lb; // (no-op guard removed below)
}

// pack 4 split values, write hi/lo as one b64 each (dst 8B-aligned)
__device__ __forceinline__ void pack_split4(const float* y,
                                            ushort_t* hdst, ushort_t* ldst) {
    ushort_t h[4], l[4];
    #pragma unroll
    for (int j = 0; j < 4; ++j) {
        __hip_bfloat16 hb = __float2bfloat16(y[j]);
        float hf = __bfloat162float(hb);
        __hip_bfloat16 lb = __float2bfloat16(y[j] - hf);
        h[j] = *(ushort_t*)&hb; l[j] = *(ushort_t*)&lb;
    }
    uint2 hv = make_uint2((unsigned)h[0] | ((unsigned)h[1] << 16),
                          (unsigned)h[2] | ((unsigned)h[3] << 16));
    uint2 lv = make_uint2((unsigned)l[0] | ((unsigned)l[1] << 16),
                          (unsigned)l[2] | ((unsigned)l[3] << 16));
    *(uint2*)hdst = hv;
    *(uint2*)ldst = lv;
}

// unswizzled fragment offset (used for W planes in global memory)
__device__ __forceinline__ int frag_off(int r, int k, int K16) {
    return (r >> 4) * K16 + (k >> 5) * 512 + ((k >> 3) & 3) * 128
         + (r & 15) * 8 + (k & 7);
}

// swizzled Y-plane offset (LDS): unit' = q*16 + ((r ^ 2q) & 15)
__device__ __forceinline__ int ywoff(int r, int k4, int K16) {
    int q = (k4 >> 3) & 3;
    int u = q * 16 + (((r & 15) ^ (q << 1)) & 15);
    return (r >> 4) * K16 + (k4 >> 5) * 512 + u * 8 + (k4 & 7);
}

// ---------------------------------------------------------------------------
// fused: full 3-layer GCN chain for one (32-row tile, batch) in LDS.
// X tensors dinv-premultiplied fp32; Y tensors bf16 hi/lo swizzled fragments.
// Y2 processed in two K-chunks through a half-size buffer (acc2 held in regs)
// so peak LDS = 53.1 KB -> 3 blocks/CU.
// ---------------------------------------------------------------------------
__global__ __launch_bounds__(256, 3) void fused(
    const float* __restrict__ Lm, const ushort_t* __restrict__ wext,
    const float* __restrict__ We, const float* __restrict__ be,
    const float* __restrict__ b1, const float* __restrict__ b2,
    const float* __restrict__ b3, float* __restrict__ partial)
{
    __shared__ __align__(16) char lds[53248];
    float*    X0   = (float*)(lds + L_X0);
    float*    lmst = (float*)(lds + L_LM);
    ushort_t* Y1h  = (ushort_t*)(lds + L_Y1);  ushort_t* Y1l = Y1h + 5120;
    float*    X1   = (float*)(lds + L_X1);
    ushort_t* Y2h  = (ushort_t*)(lds + L_Y2);  ushort_t* Y2l = Y2h + 4096;
    float*    X2   = (float*)(lds + L_X2);
    ushort_t* Y3h  = (ushort_t*)(lds + L_Y3);  ushort_t* Y3l = Y3h + 2048;
    float*    dtab = (float*)(lds + L_DTAB);
    float*    pool = (float*)(lds + L_POOL);

    const int tid  = threadIdx.x;
    const int lane = tid & 63;
    const int wave = tid >> 6;
    const int wm = wave & 1, wn = wave >> 1;
    const int l15 = lane & 15, lg = lane >> 4;
    const int lswz = (lane & 48) + (((lane & 15) ^ ((lane >> 4) << 1)) & 15);
    const int rt = blockIdx.x, b = blockIdx.y;
    const int r0 = rt * 32;

    // ---------------- stage: dinv table, landmarks, pool init -------------
    if (tid < 86) {
        int ri = r0 - 27 + tid;
        float dv = 0.f;
        if (ri >= 0 && ri < NN) {
            int lo = ri - 9; if (lo < 0) lo = 0;
            int hi = ri + 9; if (hi > NN - 1) hi = NN - 1;
            dv = 1.0f / sqrtf((float)(hi - lo + 1));
        }
        dtab[tid] = dv;
    }
    if (tid < 258) {
        int g = (r0 - 27) * 3 + tid;
        lmst[tid] = (g >= 0 && g < NN * 3) ? Lm[(size_t)b * (NN * 3) + g] : 0.f;
    }
    if (tid < 128) pool[tid] = 0.f;
    __syncthreads();

    // ---------------- encode: X0[86][68] = enc(row) * dinv -----------------
    {
        const int c = tid & 63;
        const float w0 = We[c], w1 = We[64 + c], w2 = We[128 + c], bk = be[c];
        for (int g = tid >> 6; g < 86; g += 4) {
            float x = bk + lmst[g*3]*w0 + lmst[g*3+1]*w1 + lmst[g*3+2]*w2;
            X0[g * 68 + c] = x * dtab[g];
        }
    }
    __syncthreads();

    // ---------------- band1: X0 -> Y1 (68 rows x 64), pad 68..79 -----------
    {
        const int c4 = (tid & 15) << 2;
        const int lr = (tid >> 4) * 5;             // 16 groups x 5 rows
        f32x4 ws = {};
        #pragma unroll
        for (int d = 0; d < 19; ++d)
            ws += *(const f32x4*)(X0 + (lr + d) * 68 + c4);
        #pragma unroll
        for (int rr = 0; rr < 5; ++rr) {
            if (rr) ws += *(const f32x4*)(X0 + (lr + rr + 18) * 68 + c4)
                        - *(const f32x4*)(X0 + (lr + rr - 1)  * 68 + c4);
            int row = lr + rr;
            if (row < 68) {
                float dv = dtab[row + 9];
                float y4[4] = {ws[0]*dv, ws[1]*dv, ws[2]*dv, ws[3]*dv};
                int off = ywoff(row, c4, 1024);
                pack_split4(y4, Y1h + off, Y1l + off);
            }
        }
        for (int e = tid; e < 192; e += 256) {     // zero rows 68..79
            int off = ywoff(68 + (e >> 4), (e & 15) << 2, 1024);
            *(uint2*)(Y1h + off) = make_uint2(0, 0);
            *(uint2*)(Y1l + off) = make_uint2(0, 0);
        }
    }
    __syncthreads();

    // ---------------- GEMM1: Y1(5 tiles) @ W1 ------------------------------
    f32x4 acc1[3][4] = {};
    {
        #pragma unroll
        for (int kt = 0; kt < 2; ++kt) {
            bf16x8 a[3][2];
            #pragma unroll
            for (int mt = 0; mt < 3; ++mt) {
                int off = (wm*2 + mt) * 1024 + kt * 512 + lswz * 8;
                a[mt][0] = *(const bf16x8*)(Y1h + off);
                a[mt][1] = *(const bf16x8*)(Y1l + off);
            }
            #pragma unroll
            for (int nt = 0; nt < 4; ++nt) {
                int woff = (wn*4 + nt) * 1024 + kt * 512 + lane * 8;
                bf16x8 wh = *(const bf16x8*)(wext + W1H + woff);
                bf16x8 wl = *(const bf16x8*)(wext + W1L + woff);
                #pragma unroll
                for (int mt = 0; mt < 3; ++mt) {
                    MFMA3(acc1[mt][nt], a[mt][0], a[mt][1], wh, wl);
                }
            }
        }
    }
    __syncthreads();   // all Y1 reads done before X1 overlays it

    // ---------------- epi1 -> X1[68][132] premult --------------------------
    #pragma unroll
    for (int mt = 0; mt < 3; ++mt)
    #pragma unroll
    for (int nt = 0; nt < 4; ++nt) {
        int cl = wn*64 + nt*16 + l15;
        float bv = b1[cl];
        #pragma unroll
        for (int r = 0; r < 4; ++r) {
            int lr = (wm*2 + mt)*16 + lg*4 + r;
            if (lr < 68)
                X1[lr*132 + cl] = dtab[lr + 9] * fmaxf(acc1[mt][nt][r] + bv, 0.f);
        }
    }
    __syncthreads();

    // ------- kc2 loop: band2 K-chunk -> Y2half -> GEMM2 partial ------------
    f32x4 acc2[2][8] = {};
    #pragma unroll
    for (int kc = 0; kc < 2; ++kc) {
        {   // band2 chunk: X1 cols [kc*64,+64) -> Y2half [50 rows][64], pad..63
            const int c4 = (tid & 15) << 2;
            const int lr = (tid >> 4) * 4;         // 16 groups x 4 rows
            f32x4 ws = {};
            #pragma unroll
            for (int d = 0; d < 19; ++d)
                ws += *(const f32x4*)(X1 + (lr + d) * 132 + kc*64 + c4);
            #pragma unroll
            for (int rr = 0; rr < 4; ++rr) {
                if (rr) ws += *(const f32x4*)(X1 + (lr + rr + 18) * 132 + kc*64 + c4)
                            - *(const f32x4*)(X1 + (lr + rr - 1)  * 132 + kc*64 + c4);
                int row = lr + rr;
                if (row < 50) {
                    float dv = dtab[row + 18];
                    float y4[4] = {ws[0]*dv, ws[1]*dv, ws[2]*dv, ws[3]*dv};
                    int off = ywoff(row, c4, 1024);
                    pack_split4(y4, Y2h + off, Y2l + off);
                }
            }
            for (int e = tid; e < 224; e += 256) { // zero rows 50..63
                int off = ywoff(50 + (e >> 4), (e & 15) << 2, 1024);
                *(uint2*)(Y2h + off) = make_uint2(0, 0);
                *(uint2*)(Y2l + off) = make_uint2(0, 0);
            }
        }
        __syncthreads();

        // GEMM2 partial over this K-chunk (2 kt), all N=256
        #pragma unroll
        for (int kt = 0; kt < 2; ++kt) {
            bf16x8 a[2][2];
            #pragma unroll
            for (int mt = 0; mt < 2; ++mt) {
                int off = (wm*2 + mt) * 1024 + kt * 512 + lswz * 8;
                a[mt][0] = *(const bf16x8*)(Y2h + off);
                a[mt][1] = *(const bf16x8*)(Y2l + off);
            }
            #pragma unroll
            for (int nt = 0; nt < 8; ++nt) {
                int woff = (nt*2 + wn) * 2048 + (kc*2 + kt) * 512 + lane * 8;
                bf16x8 wh = *(const bf16x8*)(wext + W2H + woff);
                bf16x8 wl = *(const bf16x8*)(wext + W2L + woff);
                #pragma unroll
                for (int mt = 0; mt < 2; ++mt) {
                    MFMA3(acc2[mt][nt], a[mt][0], a[mt][1], wh, wl);
                }
            }
        }
        __syncthreads();   // Y2half reuse next kc / X1 still needed next kc
    }

    // ------- nc loop: epi2 -> X2 -> (band3 -> Y3 -> GEMM3) x2 --------------
    f32x4 acc3[4] = {};
    #pragma unroll
    for (int nc = 0; nc < 2; ++nc) {
        // epi2 chunk -> X2 premult (X1 dead; Y2half dead)
        #pragma unroll
        for (int mt = 0; mt < 2; ++mt)
        #pragma unroll
        for (int q = 0; q < 4; ++q) {
            int ngl = (nc*4 + q) * 2*16 + wn*16 + l15;   // = (( (nc*4+q)*2 + wn )*16 + l15
            int cl = ngl - nc * 128;
            float bv = b2[ngl];
            #pragma unroll
            for (int r = 0; r < 4; ++r) {
                int lr = (wm*2 + mt)*16 + lg*4 + r;
                if (lr < 50)
                    X2[lr*132 + cl] =
                        dtab[lr + 18] * fmaxf(acc2[mt][nc*4 + q][r] + bv, 0.f);
            }
        }
        __syncthreads();

        #pragma unroll
        for (int ncc = 0; ncc < 2; ++ncc) {
            {   // band3: X2 cols [ncc*64,+64) -> Y3 [32 rows][64]
                const int c4 = (tid & 15) << 2;
                const int lr = (tid >> 4) * 2;     // 16 groups x 2 rows
                f32x4 ws = {};
                #pragma unroll
                for (int d = 0; d < 19; ++d)
                    ws += *(const f32x4*)(X2 + (lr + d) * 132 + ncc*64 + c4);
                #pragma unroll
                for (int rr = 0; rr < 2; ++rr) {
                    if (rr) ws += *(const f32x4*)(X2 + (lr+rr+18)*132 + ncc*64 + c4)
                                - *(const f32x4*)(X2 + (lr+rr-1) *132 + ncc*64 + c4);
                    int row = lr + rr;
                    float dv = dtab[row + 27];
                    float y4[4] = {ws[0]*dv, ws[1]*dv, ws[2]*dv, ws[3]*dv};
                    int off = ywoff(row, c4, 1024);
                    pack_split4(y4, Y3h + off, Y3l + off);
                }
            }
            __syncthreads();

            // GEMM3 partial (Y3 k-chunk = 64)
            #pragma unroll
            for (int kt = 0; kt < 2; ++kt) {
                int aoff = wm * 1024 + kt * 512 + lswz * 8;
                bf16x8 a0 = *(const bf16x8*)(Y3h + aoff);
                bf16x8 a1 = *(const bf16x8*)(Y3l + aoff);
                #pragma unroll
                for (int nt = 0; nt < 4; ++nt) {
                    int wkt = nc*4 + ncc*2 + kt;
                    int woff = (wn*4 + nt) * 4096 + wkt * 512 + lane * 8;
                    bf16x8 wh = *(const bf16x8*)(wext + W3H + woff);
                    bf16x8 wl = *(const bf16x8*)(wext + W3L + woff);
                    MFMA3(acc3[nt], a0, a1, wh, wl);
                }
            }
            __syncthreads();   // Y3 reuse / X2 rewrite next iteration
        }
    }

    // ---------------- pool: column sums of relu(acc3 + b3) -----------------
    #pragma unroll
    for (int nt = 0; nt < 4; ++nt) {
        float bv = b3[wn*64 + nt*16 + l15];
        float cs = 0.f;
        #pragma unroll
        for (int r = 0; r < 4; ++r) {
            int gr = r0 + wm*16 + lg*4 + r;
            if (gr < NN) cs += fmaxf(acc3[nt][r] + bv, 0.f);
        }
        cs += __shfl_xor(cs, 16);
        cs += __shfl_xor(cs, 32);
        if (lane < 16) atomicAdd(&pool[wn*64 + nt*16 + lane], cs);
    }
    __syncthreads();
    if (tid < 128) partial[((size_t)b * 15 + rt) * 128 + tid] = pool[tid];
}

// ---------------------------------------------------------------------------
// wconv: W fp32 [K][N] -> bf16 hi/lo planes, fragment layout (unswizzled)
// ---------------------------------------------------------------------------
__global__ __launch_bounds__(256) void wconv(
    const float* __restrict__ W1, const float* __restrict__ W2,
    const float* __restrict__ W3, ushort_t* __restrict__ wext)
{
    int i = blockIdx.x * 256 + threadIdx.x;
    float w; int off_h, off_l, idx;
    if (i < 8192) {                       // W1: K=64,  N=128
        int k = i >> 7, n = i & 127;
        w = W1[i]; idx = frag_off(n, k, 1024);  off_h = W1H; off_l = W1L;
    } else if (i < 40960) {               // W2: K=128, N=256
        int j = i - 8192;
        int k = j >> 8, n = j & 255;
        w = W2[j]; idx = frag_off(n, k, 2048);  off_h = W2H; off_l = W2L;
    } else if (i < 73728) {               // W3: K=256, N=128
        int j = i - 40960;
        int k = j >> 7, n = j & 127;
        w = W3[j]; idx = frag_off(n, k, 4096);  off_h = W3H; off_l = W3L;
    } else return;
    __hip_bfloat16 hb = __float2bfloat16(w);
    float hf = __bfloat162float(hb);
    __hip_bfloat16 lb = __float2bfloat16(w - hf);
    wext[off_h + idx] = *(ushort_t*)&hb;
    wext[off_l + idx] = *(ushort_t*)&lb;
}

// ---------------------------------------------------------------------------
// head: gf = mean-pool reduce; features = relu(gf@Wf+bf); out = feats@Wc+bc
// ---------------------------------------------------------------------------
__global__ __launch_bounds__(512) void head_kernel(
    const float* __restrict__ partial, const float* __restrict__ Wf,
    const float* __restrict__ bf, const float* __restrict__ Wc,
    const float* __restrict__ bc, float* __restrict__ dout)
{
    __shared__ float gfs[128];
    __shared__ float feats[512];
    int b = blockIdx.x, t = threadIdx.x;
    if (t < 128) {
        const float* p = partial + (size_t)b * (15 * 128);
        float s = 0.f;
        #pragma unroll
        for (int tt = 0; tt < 15; ++tt) s += p[tt * 128 + t];
        s *= (1.0f / 468.0f);
        gfs[t] = s;
        dout[65792 + b * 128 + t] = s;       // graph_features
    }
    __syncthreads();
    float a = bf[t];
    for (int k = 0; k < 128; ++k) a += gfs[k] * Wf[k * 512 + t];
    a = fmaxf(a, 0.f);
    dout[256 + b * 512 + t] = a;             // features
    feats[t] = a;
    __syncthreads();
    if (t < 64) {
        float s0 = 0.f, s1 = 0.f;
        for (int c = t; c < 512; c += 64) {
            float f = feats[c];
            s0 += f * Wc[c * 2 + 0];
            s1 += f * Wc[c * 2 + 1];
        }
        #pragma unroll
        for (int off = 32; off; off >>= 1) {
            s0 += __shfl_down(s0, off);
            s1 += __shfl_down(s1, off);
        }
        if (t == 0) {
            dout[b * 2 + 0] = s0 + bc[0];
            dout[b * 2 + 1] = s1 + bc[1];
        }
    }
}

// ---------------------------------------------------------------------------
extern "C" void kernel_launch(void* const* d_in, const int* in_sizes, int n_in,
                              void* d_out, int out_size, void* d_ws, size_t ws_size,
                              hipStream_t stream)
{
    const float* landmarks = (const float*)d_in[0];
    const float* W_enc     = (const float*)d_in[1];
    const float* b_enc     = (const float*)d_in[2];
    const float* W1        = (const float*)d_in[3];
    const float* b1        = (const float*)d_in[4];
    const float* W2        = (const float*)d_in[5];
    const float* b2        = (const float*)d_in[6];
    const float* W3        = (const float*)d_in[7];
    const float* b3        = (const float*)d_in[8];
    const float* W_fus     = (const float*)d_in[9];
    const float* b_fus     = (const float*)d_in[10];
    const float* W_cls     = (const float*)d_in[11];
    const float* b_cls     = (const float*)d_in[12];
    float* out = (float*)d_out;

    char* ws = (char*)d_ws;
    ushort_t* wext = (ushort_t*)(ws + 0);        // 294,912 B
    float* partial = (float*)(ws + 294912);      // 983,040 B

    wconv<<<288, 256, 0, stream>>>(W1, W2, W3, wext);
    fused<<<dim3(15, 128), 256, 0, stream>>>(
        landmarks, wext, W_enc, b_enc, b1, b2, b3, partial);
    head_kernel<<<128, 512, 0, stream>>>(partial, W_fus, b_fus, W_cls, b_cls, out);
}